// Round 1
// baseline (476.251 us; speedup 1.0000x reference)
//
#include <hip/hip_runtime.h>

// EmbeddingCRF: feats = emb[sentence] @ W^T; CRF forward (LSE), gold score,
// Viterbi decode. Parallel-in-time via 12x12 semiring chunk transfer matrices.
//
// Reduction to 12 real tags is EXACT w.r.t. the reference: all NEG=-10000
// paths contribute exp(-10000-ish)=0 in fp32 AND fp64, init handled
// analytically, terminal adds trans[STOP,:].

#define LSEQ    32768
#define NTAGS   14
#define R       12
#define T_START 12
#define T_STOP  13
#define EMBD    300
#define CCH     512   // chunks
#define SCH     64    // steps per chunk

// ws layout (float offsets)
#define OFF_FEATS 0         // [L][12] raw feats (real tags)
#define OFF_EXPF  393216    // [L][12] exp(feat - rowmax)
#define OFF_FMAX  786432    // [L] rowmax
#define OFF_PF    819200    // [C][n][p] LSE chunk matrices (log domain)
#define OFF_PFC   892928    // [C][p][n] col-major copy
#define OFF_PV    966656    // [C][n][p] max-plus chunk matrices
#define OFF_PVC   1040384   // [C][p][n] col-major copy
#define OFF_BV    1114112   // [C][12] viterbi entry vectors per chunk
#define OFF_SFX   1120256   // [C][12] viterbi suffix vectors (at chunk exit)
#define OFF_GOLD  1126400   // [1] gold score accumulator
// total floats: 1126401 (~4.3 MiB)

__device__ __forceinline__ void load12(const float* __restrict__ p, float* r) {
  const float4* p4 = (const float4*)p;
  float4 a = p4[0], b = p4[1], c = p4[2];
  r[0]=a.x; r[1]=a.y; r[2]=a.z; r[3]=a.w;
  r[4]=b.x; r[5]=b.y; r[6]=b.z; r[7]=b.w;
  r[8]=c.x; r[9]=c.y; r[10]=c.z; r[11]=c.w;
}

// ---------------- K1: feats + expfeat + featmax + gold ----------------
// 16-lane group per position, lane = tag (0..11 active).
__global__ __launch_bounds__(256) void k_feats(
    const int* __restrict__ sentence, const int* __restrict__ tags,
    const float* __restrict__ emb, const float* __restrict__ W,
    const float* __restrict__ trans, float* __restrict__ ws)
{
  __shared__ float Wl[NTAGS * EMBD];
  __shared__ float gacc;
  for (int i = threadIdx.x; i < NTAGS * EMBD; i += 256) Wl[i] = W[i];
  if (threadIdx.x == 0) gacc = 0.f;
  __syncthreads();

  int grp = threadIdx.x >> 4;
  int g   = threadIdx.x & 15;
  int pos = blockIdx.x * 16 + grp;
  int row = sentence[pos];

  float acc = 0.f;
  if (g < R) {
    const float4* e4 = (const float4*)(emb + (size_t)row * EMBD);
    const float4* w4 = (const float4*)(Wl + g * EMBD);
    #pragma unroll 5
    for (int i = 0; i < EMBD / 4; ++i) {
      float4 a = e4[i]; float4 b = w4[i];
      acc += a.x*b.x + a.y*b.y + a.z*b.z + a.w*b.w;
    }
  }
  float feat = (g < R) ? acc : -3.0e38f;
  float mx = feat;
  #pragma unroll
  for (int off = 1; off < 16; off <<= 1)
    mx = fmaxf(mx, __shfl_xor(mx, off, 16));

  if (g < R) {
    ws[OFF_FEATS + pos * 12 + g] = feat;
    ws[OFF_EXPF  + pos * 12 + g] = __expf(feat - mx);
  }
  if (g == 0) ws[OFF_FMAX + pos] = mx;

  int tg = tags[pos];
  if (g == tg) {
    int prev = (pos == 0) ? T_START : tags[pos - 1];
    float gc = feat + trans[tg * NTAGS + prev];
    if (pos == LSEQ - 1) gc += trans[T_STOP * NTAGS + tg];
    atomicAdd(&gacc, gc);
  }
  __syncthreads();
  if (threadIdx.x == 0) atomicAdd(&ws[OFF_GOLD], gacc);
}

// ---------------- K2: chunk transfer matrices, both semirings ----------------
// lane = (sub-chunk q, basis column p). 144-entry transition matrix kept in
// registers (wave-uniform). Forward in exp domain w/ pow2 rescale every 8 steps.
__global__ __launch_bounds__(64, 1) void k_pass1(
    const float* __restrict__ trans, float* __restrict__ ws)
{
  int role = blockIdx.x >> 7;            // 0: LSE forward, 1: viterbi
  int q = threadIdx.x >> 4;
  int p = threadIdx.x & 15;
  int c = (blockIdx.x & 127) * 4 + q;
  int t0 = (c == 0) ? 1 : c * SCH;
  int t1 = c * SCH + SCH;
  bool act = (p < R);

  float Treg[R][R];

  if (role == 0) {
    #pragma unroll
    for (int n = 0; n < R; ++n)
      #pragma unroll
      for (int m = 0; m < R; ++m)
        Treg[n][m] = __expf(trans[n * NTAGS + m]);

    float E[R];
    #pragma unroll
    for (int m = 0; m < R; ++m) E[m] = (m == p) ? 1.f : 0.f;
    int kacc = 0;
    float sfeat = 0.f;

    for (int t = t0; t < t1; ++t) {
      float ef[R];
      load12(ws + OFF_EXPF + t * 12, ef);
      sfeat += ws[OFF_FMAX + t];
      float NE[R];
      #pragma unroll
      for (int n = 0; n < R; ++n) {
        float s = Treg[n][0] * E[0];
        #pragma unroll
        for (int m = 1; m < R; ++m) s = fmaf(Treg[n][m], E[m], s);
        NE[n] = s * ef[n];
      }
      #pragma unroll
      for (int n = 0; n < R; ++n) E[n] = NE[n];
      if ((t & 7) == 7) {
        float mx = E[0];
        #pragma unroll
        for (int n = 1; n < R; ++n) mx = fmaxf(mx, E[n]);
        if (mx > 0.f) {
          int k = ((__float_as_int(mx) >> 23) & 0xFF) - 127;
          float sc = __int_as_float((127 - k) << 23);
          #pragma unroll
          for (int n = 0; n < R; ++n) E[n] *= sc;
          kacc += k;
        }
      }
    }
    if (act) {
      float base = (float)kacc * 0.6931471805599453f + sfeat;
      #pragma unroll
      for (int n = 0; n < R; ++n) {
        float v = (E[n] > 0.f) ? (__logf(E[n]) + base) : -1.0e30f;
        ws[OFF_PF  + c * 144 + n * 12 + p] = v;
        ws[OFF_PFC + c * 144 + p * 12 + n] = v;
      }
    }
  } else {
    #pragma unroll
    for (int n = 0; n < R; ++n)
      #pragma unroll
      for (int m = 0; m < R; ++m)
        Treg[n][m] = trans[n * NTAGS + m];

    float V[R];
    #pragma unroll
    for (int m = 0; m < R; ++m) V[m] = (m == p) ? 0.f : -1.0e30f;

    for (int t = t0; t < t1; ++t) {
      float fr[R];
      load12(ws + OFF_FEATS + t * 12, fr);
      float NV[R];
      #pragma unroll
      for (int n = 0; n < R; ++n) {
        float b = Treg[n][0] + V[0];
        #pragma unroll
        for (int m = 1; m < R; ++m) b = fmaxf(b, Treg[n][m] + V[m]);
        NV[n] = b + fr[n];
      }
      #pragma unroll
      for (int n = 0; n < R; ++n) V[n] = NV[n];
    }
    if (act) {
      #pragma unroll
      for (int n = 0; n < R; ++n) {
        ws[OFF_PV  + c * 144 + n * 12 + p] = V[n];
        ws[OFF_PVC + c * 144 + p * 12 + n] = V[n];
      }
    }
  }
}

// ---------------- K3: sequential chunk-level scans (1 block, 4 waves) --------
__global__ __launch_bounds__(256) void k_scan(
    const float* __restrict__ trans, float* __restrict__ ws,
    float* __restrict__ out)
{
  __shared__ float lv_sh[R];
  int wid  = threadIdx.x >> 6;
  int lane = threadIdx.x & 63;
  int n = lane;
  bool act = (lane < R);
  float u[R];   // replicated vector (used by waves for final combines)

  if (wid == 0) {
    // Viterbi forward boundary vectors
    float x = -3.0e38f;
    if (act) {
      x = trans[n * NTAGS + T_START] + ws[OFF_FEATS + n];
      ws[OFF_BV + n] = x;
    }
    float v[R];
    #pragma unroll
    for (int m = 0; m < R; ++m) v[m] = __shfl(x, m, 64);
    for (int c = 0; c < CCH; ++c) {
      float nx = -3.0e38f;
      if (act) {
        float rr[R];
        load12(ws + OFF_PV + c * 144 + n * 12, rr);
        nx = rr[0] + v[0];
        #pragma unroll
        for (int m = 1; m < R; ++m) nx = fmaxf(nx, rr[m] + v[m]);
        if (c < CCH - 1) ws[OFF_BV + (c + 1) * 12 + n] = nx;
      }
      #pragma unroll
      for (int m = 0; m < R; ++m) v[m] = __shfl(nx, m, 64);
    }
    float ps = -3.0e38f;
    #pragma unroll
    for (int m = 0; m < R; ++m) ps = fmaxf(ps, v[m] + trans[T_STOP * NTAGS + m]);
    if (lane == 0) out[1] = ps;
  } else if (wid == 1) {
    // Viterbi suffix vectors (transpose application, col-major matrices)
    float x = -3.0e38f;
    if (act) {
      x = trans[T_STOP * NTAGS + n];
      ws[OFF_SFX + (CCH - 1) * 12 + n] = x;
    }
    float v[R];
    #pragma unroll
    for (int m = 0; m < R; ++m) v[m] = __shfl(x, m, 64);
    for (int c = CCH - 1; c >= 1; --c) {
      float nx = -3.0e38f;
      if (act) {
        float rr[R];
        load12(ws + OFF_PVC + c * 144 + n * 12, rr);
        nx = rr[0] + v[0];
        #pragma unroll
        for (int m = 1; m < R; ++m) nx = fmaxf(nx, rr[m] + v[m]);
        ws[OFF_SFX + (c - 1) * 12 + n] = nx;
      }
      #pragma unroll
      for (int m = 0; m < R; ++m) v[m] = __shfl(nx, m, 64);
    }
  } else if (wid == 2) {
    // LSE left half (chunks 0..255), forward
    float x = -3.0e38f;
    if (act) x = trans[n * NTAGS + T_START] + ws[OFF_FEATS + n];
    float v[R];
    #pragma unroll
    for (int m = 0; m < R; ++m) v[m] = __shfl(x, m, 64);
    for (int c = 0; c < CCH / 2; ++c) {
      float nx = -3.0e38f;
      if (act) {
        float rr[R];
        load12(ws + OFF_PF + c * 144 + n * 12, rr);
        float tv[R]; float mx = -3.0e38f;
        #pragma unroll
        for (int m = 0; m < R; ++m) { tv[m] = rr[m] + v[m]; mx = fmaxf(mx, tv[m]); }
        float s = 0.f;
        #pragma unroll
        for (int m = 0; m < R; ++m) s += __expf(tv[m] - mx);
        nx = mx + __logf(s);
      }
      #pragma unroll
      for (int m = 0; m < R; ++m) v[m] = __shfl(nx, m, 64);
    }
    if (act) lv_sh[n] = v[n];
  } else {
    // LSE right half (chunks 511..256), backward transpose
    float x = -3.0e38f;
    if (act) x = trans[T_STOP * NTAGS + n];
    #pragma unroll
    for (int m = 0; m < R; ++m) u[m] = __shfl(x, m, 64);
    for (int c = CCH - 1; c >= CCH / 2; --c) {
      float nx = -3.0e38f;
      if (act) {
        float rr[R];
        load12(ws + OFF_PFC + c * 144 + n * 12, rr);
        float tv[R]; float mx = -3.0e38f;
        #pragma unroll
        for (int m = 0; m < R; ++m) { tv[m] = rr[m] + u[m]; mx = fmaxf(mx, tv[m]); }
        float s = 0.f;
        #pragma unroll
        for (int m = 0; m < R; ++m) s += __expf(tv[m] - mx);
        nx = mx + __logf(s);
      }
      #pragma unroll
      for (int m = 0; m < R; ++m) u[m] = __shfl(nx, m, 64);
    }
  }
  __syncthreads();
  if (wid == 3 && lane == 0) {
    float mx = -3.0e38f;
    #pragma unroll
    for (int m = 0; m < R; ++m) mx = fmaxf(mx, lv_sh[m] + u[m]);
    float s = 0.f;
    #pragma unroll
    for (int m = 0; m < R; ++m) s += __expf(lv_sh[m] + u[m] - mx);
    float fwd = mx + __logf(s);
    out[0] = fwd - ws[OFF_GOLD];
  }
}

// ---------------- K4: per-chunk Viterbi decode ----------------
// 16-lane group per chunk (lane = tag). Exit tag via argmax(fv_end + suffix).
__global__ __launch_bounds__(64) void k_decode(
    const float* __restrict__ trans, const float* __restrict__ ws,
    float* __restrict__ out)
{
  __shared__ unsigned char bp[4][SCH][16];
  int q = threadIdx.x >> 4;
  int g = threadIdx.x & 15;
  int c = blockIdx.x * 4 + q;
  int t0 = (c == 0) ? 1 : c * SCH;
  int t1 = c * SCH + SCH;
  bool act = (g < R);

  float treg[R];
  if (act) {
    #pragma unroll
    for (int m = 0; m < R; ++m) treg[m] = trans[g * NTAGS + m];
  }
  float fv = -3.0e38f;
  if (act) fv = ws[OFF_BV + c * 12 + g];

  for (int t = t0; t < t1; ++t) {
    float best = -3.0e38f; int bi = 0;
    #pragma unroll
    for (int m = 0; m < R; ++m) {
      float o = __shfl(fv, m, 16);
      if (act) {
        float cand = treg[m] + o;
        if (cand > best) { best = cand; bi = m; }
      }
    }
    float nfv = -3.0e38f;
    if (act) {
      nfv = best + ws[OFF_FEATS + t * 12 + g];
      bp[q][t - t0][g] = (unsigned char)bi;
    }
    fv = nfv;
  }
  __syncthreads();

  float term = -3.0e38f; int idx = 15;
  if (act) { term = fv + ws[OFF_SFX + c * 12 + g]; idx = g; }
  #pragma unroll
  for (int off = 1; off < 16; off <<= 1) {
    float ov = __shfl_xor(term, off, 16);
    int   oi = __shfl_xor(idx,  off, 16);
    if (ov > term || (ov == term && oi < idx)) { term = ov; idx = oi; }
  }

  if (g == 0) {
    int cur = idx;
    int len = t1 - t0;
    out[2 + t0 + len - 1] = (float)cur;
    for (int tt = len - 1; tt >= 1; --tt) {
      cur = bp[q][tt][cur];
      out[2 + t0 + tt - 1] = (float)cur;
    }
    if (c == 0) {
      cur = bp[q][0][cur];
      out[2 + 0] = (float)cur;
    }
  }
}

extern "C" void kernel_launch(void* const* d_in, const int* in_sizes, int n_in,
                              void* d_out, int out_size, void* d_ws, size_t ws_size,
                              hipStream_t stream) {
  (void)in_sizes; (void)n_in; (void)out_size; (void)ws_size;
  const int*   sentence = (const int*)d_in[0];
  const int*   tags     = (const int*)d_in[1];
  const float* emb      = (const float*)d_in[2];
  const float* W        = (const float*)d_in[3];
  const float* trans    = (const float*)d_in[4];
  float* ws  = (float*)d_ws;
  float* out = (float*)d_out;

  hipMemsetAsync(ws + OFF_GOLD, 0, sizeof(float), stream);
  k_feats<<<LSEQ / 16, 256, 0, stream>>>(sentence, tags, emb, W, trans, ws);
  k_pass1<<<256, 64, 0, stream>>>(trans, ws);
  k_scan<<<1, 256, 0, stream>>>(trans, ws, out);
  k_decode<<<CCH / 4, 64, 0, stream>>>(trans, ws, out);
}

// Round 2
// 372.782 us; speedup vs baseline: 1.2776x; 1.2776x over previous
//
#include <hip/hip_runtime.h>

// EmbeddingCRF: feats = emb[sentence] @ W^T; CRF forward (LSE), gold score,
// Viterbi decode. Parallel-in-time via 12x12 semiring chunk transfer matrices,
// now with a 3-level scan: 512 chunks -> 32 super-chunks -> sequential 32.
//
// Reduction to 12 real tags is EXACT w.r.t. the reference: all NEG=-10000
// paths contribute exp(-10000-ish)=0 in fp32 AND fp64, init handled
// analytically, terminal adds trans[STOP,:].

#define LSEQ    32768
#define NTAGS   14
#define R       12
#define T_START 12
#define T_STOP  13
#define EMBD    300
#define CCH     512   // chunks
#define SCH     64    // steps per chunk
#define NSUP    32    // super-chunks
#define CPS     16    // chunks per super-chunk

// ws layout (float offsets)
#define OFF_FEATS 0         // [L][12] raw feats (real tags)
#define OFF_EXPF  393216    // [L][12] exp(feat - rowmax)
#define OFF_FMAX  786432    // [L] rowmax
#define OFF_PF    819200    // [C][n][p] LSE chunk matrices (log domain)
#define OFF_PFC   892928    // [C][p][n] col-major copy
#define OFF_PV    966656    // [C][n][p] max-plus chunk matrices
#define OFF_PVC   1040384   // [C][p][n] col-major copy
#define OFF_BV    1114112   // [C][12] viterbi entry vectors per chunk
#define OFF_SFX   1120256   // [C][12] viterbi suffix vectors (at chunk exit)
#define OFF_GOLD  1126400   // [1] gold score accumulator
#define OFF_SMV   1130496   // [32][n][p] super viterbi matrices (row-major)
#define OFF_SMVT  1135104   // [32][p][n] transposed
#define OFF_SMF   1139712   // [32][n][p] super LSE matrices (log domain)
#define OFF_SBV   1144320   // [32][12] super entry vectors
#define OFF_SSFX  1144704   // [32][12] super suffix vectors
// total floats: ~1145088 (~4.37 MiB)

__device__ __forceinline__ void load12(const float* __restrict__ p, float* r) {
  const float4* p4 = (const float4*)p;
  float4 a = p4[0], b = p4[1], c = p4[2];
  r[0]=a.x; r[1]=a.y; r[2]=a.z; r[3]=a.w;
  r[4]=b.x; r[5]=b.y; r[6]=b.z; r[7]=b.w;
  r[8]=c.x; r[9]=c.y; r[10]=c.z; r[11]=c.w;
}

// ---------------- K1: feats + expfeat + featmax + gold ----------------
// 16-lane group per position, lane = tag (0..11 active).
__global__ __launch_bounds__(256) void k_feats(
    const int* __restrict__ sentence, const int* __restrict__ tags,
    const float* __restrict__ emb, const float* __restrict__ W,
    const float* __restrict__ trans, float* __restrict__ ws)
{
  __shared__ float Wl[NTAGS * EMBD];
  __shared__ float gacc;
  for (int i = threadIdx.x; i < NTAGS * EMBD; i += 256) Wl[i] = W[i];
  if (threadIdx.x == 0) gacc = 0.f;
  __syncthreads();

  int grp = threadIdx.x >> 4;
  int g   = threadIdx.x & 15;
  int pos = blockIdx.x * 16 + grp;
  int row = sentence[pos];

  float acc = 0.f;
  if (g < R) {
    const float4* e4 = (const float4*)(emb + (size_t)row * EMBD);
    const float4* w4 = (const float4*)(Wl + g * EMBD);
    #pragma unroll 5
    for (int i = 0; i < EMBD / 4; ++i) {
      float4 a = e4[i]; float4 b = w4[i];
      acc += a.x*b.x + a.y*b.y + a.z*b.z + a.w*b.w;
    }
  }
  float feat = (g < R) ? acc : -3.0e38f;
  float mx = feat;
  #pragma unroll
  for (int off = 1; off < 16; off <<= 1)
    mx = fmaxf(mx, __shfl_xor(mx, off, 16));

  if (g < R) {
    ws[OFF_FEATS + pos * 12 + g] = feat;
    ws[OFF_EXPF  + pos * 12 + g] = __expf(feat - mx);
  }
  if (g == 0) ws[OFF_FMAX + pos] = mx;

  int tg = tags[pos];
  if (g == tg) {
    int prev = (pos == 0) ? T_START : tags[pos - 1];
    float gc = feat + trans[tg * NTAGS + prev];
    if (pos == LSEQ - 1) gc += trans[T_STOP * NTAGS + tg];
    atomicAdd(&gacc, gc);
  }
  __syncthreads();
  if (threadIdx.x == 0) atomicAdd(&ws[OFF_GOLD], gacc);
}

// ---------------- K2: chunk transfer matrices, both semirings ----------------
__global__ __launch_bounds__(64, 1) void k_pass1(
    const float* __restrict__ trans, float* __restrict__ ws)
{
  int role = blockIdx.x >> 7;            // 0: LSE forward, 1: viterbi
  int q = threadIdx.x >> 4;
  int p = threadIdx.x & 15;
  int c = (blockIdx.x & 127) * 4 + q;
  int t0 = (c == 0) ? 1 : c * SCH;
  int t1 = c * SCH + SCH;
  bool act = (p < R);

  float Treg[R][R];

  if (role == 0) {
    #pragma unroll
    for (int n = 0; n < R; ++n)
      #pragma unroll
      for (int m = 0; m < R; ++m)
        Treg[n][m] = __expf(trans[n * NTAGS + m]);

    float E[R];
    #pragma unroll
    for (int m = 0; m < R; ++m) E[m] = (m == p) ? 1.f : 0.f;
    int kacc = 0;
    float sfeat = 0.f;

    for (int t = t0; t < t1; ++t) {
      float ef[R];
      load12(ws + OFF_EXPF + t * 12, ef);
      sfeat += ws[OFF_FMAX + t];
      float NE[R];
      #pragma unroll
      for (int n = 0; n < R; ++n) {
        float s = Treg[n][0] * E[0];
        #pragma unroll
        for (int m = 1; m < R; ++m) s = fmaf(Treg[n][m], E[m], s);
        NE[n] = s * ef[n];
      }
      #pragma unroll
      for (int n = 0; n < R; ++n) E[n] = NE[n];
      if ((t & 7) == 7) {
        float mx = E[0];
        #pragma unroll
        for (int n = 1; n < R; ++n) mx = fmaxf(mx, E[n]);
        if (mx > 0.f) {
          int k = ((__float_as_int(mx) >> 23) & 0xFF) - 127;
          float sc = __int_as_float((127 - k) << 23);
          #pragma unroll
          for (int n = 0; n < R; ++n) E[n] *= sc;
          kacc += k;
        }
      }
    }
    if (act) {
      float base = (float)kacc * 0.6931471805599453f + sfeat;
      #pragma unroll
      for (int n = 0; n < R; ++n) {
        float v = (E[n] > 0.f) ? (__logf(E[n]) + base) : -1.0e30f;
        ws[OFF_PF  + c * 144 + n * 12 + p] = v;
        ws[OFF_PFC + c * 144 + p * 12 + n] = v;
      }
    }
  } else {
    #pragma unroll
    for (int n = 0; n < R; ++n)
      #pragma unroll
      for (int m = 0; m < R; ++m)
        Treg[n][m] = trans[n * NTAGS + m];

    float V[R];
    #pragma unroll
    for (int m = 0; m < R; ++m) V[m] = (m == p) ? 0.f : -1.0e30f;

    for (int t = t0; t < t1; ++t) {
      float fr[R];
      load12(ws + OFF_FEATS + t * 12, fr);
      float NV[R];
      #pragma unroll
      for (int n = 0; n < R; ++n) {
        float b = Treg[n][0] + V[0];
        #pragma unroll
        for (int m = 1; m < R; ++m) b = fmaxf(b, Treg[n][m] + V[m]);
        NV[n] = b + fr[n];
      }
      #pragma unroll
      for (int n = 0; n < R; ++n) V[n] = NV[n];
    }
    if (act) {
      #pragma unroll
      for (int n = 0; n < R; ++n) {
        ws[OFF_PV  + c * 144 + n * 12 + p] = V[n];
        ws[OFF_PVC + c * 144 + p * 12 + n] = V[n];
      }
    }
  }
}

// ---------------- K2.5: super-chunk matrices (fold 16 chunk mats) -----------
// 64 tasks: gid = s*2+sem; sem 0 = viterbi (max-plus), 1 = LSE (log-domain).
// 16-lane group per task, lane p = basis column of accumulated product.
__global__ __launch_bounds__(64) void k_super(
    float* __restrict__ ws)
{
  int q   = threadIdx.x >> 4;
  int p   = threadIdx.x & 15;
  int gid = blockIdx.x * 4 + q;
  int s   = gid >> 1;
  int sem = gid & 1;
  bool act = (p < R);

  float v[R];
  #pragma unroll
  for (int m = 0; m < R; ++m) v[m] = (m == p) ? 0.f : -1.0e30f;

  if (sem == 0) {
    for (int j = 0; j < CPS; ++j) {
      int c = s * CPS + j;
      float nv[R];
      if (act) {
        #pragma unroll
        for (int n = 0; n < R; ++n) {
          float rr[R];
          load12(ws + OFF_PV + c * 144 + n * 12, rr);
          float b = rr[0] + v[0];
          #pragma unroll
          for (int m = 1; m < R; ++m) b = fmaxf(b, rr[m] + v[m]);
          nv[n] = b;
        }
        #pragma unroll
        for (int n = 0; n < R; ++n) v[n] = nv[n];
      }
    }
    if (act) {
      #pragma unroll
      for (int n = 0; n < R; ++n) {
        ws[OFF_SMV  + s * 144 + n * 12 + p] = v[n];
        ws[OFF_SMVT + s * 144 + p * 12 + n] = v[n];
      }
    }
  } else {
    for (int j = 0; j < CPS; ++j) {
      int c = s * CPS + j;
      float nv[R];
      if (act) {
        #pragma unroll
        for (int n = 0; n < R; ++n) {
          float rr[R];
          load12(ws + OFF_PF + c * 144 + n * 12, rr);
          float tv[R]; float mx = -3.0e38f;
          #pragma unroll
          for (int m = 0; m < R; ++m) { tv[m] = rr[m] + v[m]; mx = fmaxf(mx, tv[m]); }
          float sum = 0.f;
          #pragma unroll
          for (int m = 0; m < R; ++m) sum += __expf(tv[m] - mx);
          nv[n] = mx + __logf(sum);
        }
        #pragma unroll
        for (int n = 0; n < R; ++n) v[n] = nv[n];
      }
    }
    if (act) {
      #pragma unroll
      for (int n = 0; n < R; ++n)
        ws[OFF_SMF + s * 144 + n * 12 + p] = v[n];
    }
  }
}

// ---------------- K3: sequential super-level scans (1 block, 3 waves) -------
__global__ __launch_bounds__(256) void k_mid(
    const float* __restrict__ trans, float* __restrict__ ws,
    float* __restrict__ out)
{
  int wid  = threadIdx.x >> 6;
  int lane = threadIdx.x & 63;
  int n = lane;
  bool act = (lane < R);

  if (wid == 0) {
    // Viterbi forward over super matrices -> SBV + path_score
    float x = -3.0e38f;
    if (act) {
      x = trans[n * NTAGS + T_START] + ws[OFF_FEATS + n];
      ws[OFF_SBV + n] = x;
    }
    float v[R];
    #pragma unroll
    for (int m = 0; m < R; ++m) v[m] = __shfl(x, m, 64);
    for (int s = 0; s < NSUP; ++s) {
      float nx = -3.0e38f;
      if (act) {
        float rr[R];
        load12(ws + OFF_SMV + s * 144 + n * 12, rr);
        nx = rr[0] + v[0];
        #pragma unroll
        for (int m = 1; m < R; ++m) nx = fmaxf(nx, rr[m] + v[m]);
        if (s < NSUP - 1) ws[OFF_SBV + (s + 1) * 12 + n] = nx;
      }
      #pragma unroll
      for (int m = 0; m < R; ++m) v[m] = __shfl(nx, m, 64);
    }
    if (lane == 0) {
      float ps = -3.0e38f;
      #pragma unroll
      for (int m = 0; m < R; ++m) ps = fmaxf(ps, v[m] + trans[T_STOP * NTAGS + m]);
      out[1] = ps;
    }
  } else if (wid == 1) {
    // Viterbi suffix over transposed super matrices -> SSFX
    float x = -3.0e38f;
    if (act) {
      x = trans[T_STOP * NTAGS + n];
      ws[OFF_SSFX + (NSUP - 1) * 12 + n] = x;
    }
    float v[R];
    #pragma unroll
    for (int m = 0; m < R; ++m) v[m] = __shfl(x, m, 64);
    for (int s = NSUP - 1; s >= 1; --s) {
      float nx = -3.0e38f;
      if (act) {
        float rr[R];
        load12(ws + OFF_SMVT + s * 144 + n * 12, rr);
        nx = rr[0] + v[0];
        #pragma unroll
        for (int m = 1; m < R; ++m) nx = fmaxf(nx, rr[m] + v[m]);
        ws[OFF_SSFX + (s - 1) * 12 + n] = nx;
      }
      #pragma unroll
      for (int m = 0; m < R; ++m) v[m] = __shfl(nx, m, 64);
    }
  } else if (wid == 2) {
    // LSE forward over super matrices -> nll
    float x = -3.0e38f;
    if (act) x = trans[n * NTAGS + T_START] + ws[OFF_FEATS + n];
    float v[R];
    #pragma unroll
    for (int m = 0; m < R; ++m) v[m] = __shfl(x, m, 64);
    for (int s = 0; s < NSUP; ++s) {
      float nx = -3.0e38f;
      if (act) {
        float rr[R];
        load12(ws + OFF_SMF + s * 144 + n * 12, rr);
        float tv[R]; float mx = -3.0e38f;
        #pragma unroll
        for (int m = 0; m < R; ++m) { tv[m] = rr[m] + v[m]; mx = fmaxf(mx, tv[m]); }
        float sum = 0.f;
        #pragma unroll
        for (int m = 0; m < R; ++m) sum += __expf(tv[m] - mx);
        nx = mx + __logf(sum);
      }
      #pragma unroll
      for (int m = 0; m < R; ++m) v[m] = __shfl(nx, m, 64);
    }
    if (lane == 0) {
      float mx = -3.0e38f;
      #pragma unroll
      for (int m = 0; m < R; ++m) mx = fmaxf(mx, v[m] + trans[T_STOP * NTAGS + m]);
      float sum = 0.f;
      #pragma unroll
      for (int m = 0; m < R; ++m) sum += __expf(v[m] + trans[T_STOP * NTAGS + m] - mx);
      out[0] = (mx + __logf(sum)) - ws[OFF_GOLD];
    }
  }
}

// ---------------- K3.5: expand super vectors to per-chunk BV / SFX ----------
// 64 tasks: gid = s*2+dir; dir 0 = entry vectors (fwd), 1 = suffix (bwd).
// 16-lane group per task, lane n = state component.
__global__ __launch_bounds__(64) void k_expand(
    float* __restrict__ ws)
{
  int q   = threadIdx.x >> 4;
  int n   = threadIdx.x & 15;
  int gid = blockIdx.x * 4 + q;
  int s   = gid >> 1;
  int dir = gid & 1;
  bool act = (n < R);

  if (dir == 0) {
    float x = -3.0e38f;
    if (act) {
      x = ws[OFF_SBV + s * 12 + n];
      ws[OFF_BV + (s * CPS) * 12 + n] = x;
    }
    float v[R];
    #pragma unroll
    for (int m = 0; m < R; ++m) v[m] = __shfl(x, m, 16);
    for (int j = 0; j < CPS - 1; ++j) {
      int c = s * CPS + j;
      float nx = -3.0e38f;
      if (act) {
        float rr[R];
        load12(ws + OFF_PV + c * 144 + n * 12, rr);
        nx = rr[0] + v[0];
        #pragma unroll
        for (int m = 1; m < R; ++m) nx = fmaxf(nx, rr[m] + v[m]);
        ws[OFF_BV + (c + 1) * 12 + n] = nx;
      }
      #pragma unroll
      for (int m = 0; m < R; ++m) v[m] = __shfl(nx, m, 16);
    }
  } else {
    float x = -3.0e38f;
    if (act) {
      x = ws[OFF_SSFX + s * 12 + n];
      ws[OFF_SFX + (s * CPS + CPS - 1) * 12 + n] = x;
    }
    float v[R];
    #pragma unroll
    for (int m = 0; m < R; ++m) v[m] = __shfl(x, m, 16);
    for (int j = CPS - 1; j >= 1; --j) {
      int c = s * CPS + j;
      float nx = -3.0e38f;
      if (act) {
        float rr[R];
        load12(ws + OFF_PVC + c * 144 + n * 12, rr);
        nx = rr[0] + v[0];
        #pragma unroll
        for (int m = 1; m < R; ++m) nx = fmaxf(nx, rr[m] + v[m]);
        ws[OFF_SFX + (c - 1) * 12 + n] = nx;
      }
      #pragma unroll
      for (int m = 0; m < R; ++m) v[m] = __shfl(nx, m, 16);
    }
  }
}

// ---------------- K4: per-chunk Viterbi decode ----------------
__global__ __launch_bounds__(64) void k_decode(
    const float* __restrict__ trans, const float* __restrict__ ws,
    float* __restrict__ out)
{
  __shared__ unsigned char bp[4][SCH][16];
  int q = threadIdx.x >> 4;
  int g = threadIdx.x & 15;
  int c = blockIdx.x * 4 + q;
  int t0 = (c == 0) ? 1 : c * SCH;
  int t1 = c * SCH + SCH;
  bool act = (g < R);

  float treg[R];
  if (act) {
    #pragma unroll
    for (int m = 0; m < R; ++m) treg[m] = trans[g * NTAGS + m];
  }
  float fv = -3.0e38f;
  if (act) fv = ws[OFF_BV + c * 12 + g];

  for (int t = t0; t < t1; ++t) {
    float best = -3.0e38f; int bi = 0;
    #pragma unroll
    for (int m = 0; m < R; ++m) {
      float o = __shfl(fv, m, 16);
      if (act) {
        float cand = treg[m] + o;
        if (cand > best) { best = cand; bi = m; }
      }
    }
    float nfv = -3.0e38f;
    if (act) {
      nfv = best + ws[OFF_FEATS + t * 12 + g];
      bp[q][t - t0][g] = (unsigned char)bi;
    }
    fv = nfv;
  }
  __syncthreads();

  float term = -3.0e38f; int idx = 15;
  if (act) { term = fv + ws[OFF_SFX + c * 12 + g]; idx = g; }
  #pragma unroll
  for (int off = 1; off < 16; off <<= 1) {
    float ov = __shfl_xor(term, off, 16);
    int   oi = __shfl_xor(idx,  off, 16);
    if (ov > term || (ov == term && oi < idx)) { term = ov; idx = oi; }
  }

  if (g == 0) {
    int cur = idx;
    int len = t1 - t0;
    out[2 + t0 + len - 1] = (float)cur;
    for (int tt = len - 1; tt >= 1; --tt) {
      cur = bp[q][tt][cur];
      out[2 + t0 + tt - 1] = (float)cur;
    }
    if (c == 0) {
      cur = bp[q][0][cur];
      out[2 + 0] = (float)cur;
    }
  }
}

extern "C" void kernel_launch(void* const* d_in, const int* in_sizes, int n_in,
                              void* d_out, int out_size, void* d_ws, size_t ws_size,
                              hipStream_t stream) {
  (void)in_sizes; (void)n_in; (void)out_size; (void)ws_size;
  const int*   sentence = (const int*)d_in[0];
  const int*   tags     = (const int*)d_in[1];
  const float* emb      = (const float*)d_in[2];
  const float* W        = (const float*)d_in[3];
  const float* trans    = (const float*)d_in[4];
  float* ws  = (float*)d_ws;
  float* out = (float*)d_out;

  hipMemsetAsync(ws + OFF_GOLD, 0, sizeof(float), stream);
  k_feats<<<LSEQ / 16, 256, 0, stream>>>(sentence, tags, emb, W, trans, ws);
  k_pass1<<<256, 64, 0, stream>>>(trans, ws);
  k_super<<<16, 64, 0, stream>>>(ws);
  k_mid<<<1, 256, 0, stream>>>(trans, ws, out);
  k_expand<<<16, 64, 0, stream>>>(ws);
  k_decode<<<CCH / 4, 64, 0, stream>>>(trans, ws, out);
}

// Round 3
// 306.175 us; speedup vs baseline: 1.5555x; 1.2175x over previous
//
#include <hip/hip_runtime.h>

// EmbeddingCRF: feats = emb[sentence] @ W^T; CRF forward (LSE), gold score,
// Viterbi decode. Parallel-in-time via 12x12 semiring chunk transfer matrices.
// 3-level scan: 512 chunks -> 32 super-chunks -> sequential 32.
// R3: latency-tolerant rewrites — LDS-staged parallel super-folds, explicit
// prefetch in all serial loops, LDS broadcast instead of shuffle chains.

#define LSEQ    32768
#define NTAGS   14
#define R       12
#define T_START 12
#define T_STOP  13
#define EMBD    300
#define CCH     512   // chunks
#define SCH     64    // steps per chunk
#define NSUP    32    // super-chunks
#define CPS     16    // chunks per super-chunk

// ws layout (float offsets)
#define OFF_FEATS 0         // [L][12] raw feats (real tags)
#define OFF_EXPF  393216    // [L][12] exp(feat - rowmax)
#define OFF_FMAX  786432    // [L] rowmax
#define OFF_PF    819200    // [C][n][p] LSE chunk matrices (log domain)
#define OFF_PFC   892928    // [C][p][n] col-major copy
#define OFF_PV    966656    // [C][n][p] max-plus chunk matrices
#define OFF_PVC   1040384   // [C][p][n] col-major copy
#define OFF_BV    1114112   // [C][12] viterbi entry vectors per chunk
#define OFF_SFX   1120256   // [C][12] viterbi suffix vectors (at chunk exit)
#define OFF_GOLD  1126400   // [1] gold score accumulator
#define OFF_SMV   1130496   // [32][n][p] super viterbi matrices (row-major)
#define OFF_SMVT  1135104   // [32][p][n] transposed
#define OFF_SMF   1139712   // [32][n][p] super LSE matrices (log domain)
#define OFF_SBV   1144320   // [32][12] super entry vectors
#define OFF_SSFX  1144704   // [32][12] super suffix vectors

__device__ __forceinline__ void load12(const float* __restrict__ p, float* r) {
  const float4* p4 = (const float4*)p;
  float4 a = p4[0], b = p4[1], c = p4[2];
  r[0]=a.x; r[1]=a.y; r[2]=a.z; r[3]=a.w;
  r[4]=b.x; r[5]=b.y; r[6]=b.z; r[7]=b.w;
  r[8]=c.x; r[9]=c.y; r[10]=c.z; r[11]=c.w;
}

__device__ __forceinline__ void lds12(const float* p, float* r) {
  const float4* p4 = (const float4*)p;
  float4 a = p4[0], b = p4[1], c = p4[2];
  r[0]=a.x; r[1]=a.y; r[2]=a.z; r[3]=a.w;
  r[4]=b.x; r[5]=b.y; r[6]=b.z; r[7]=b.w;
  r[8]=c.x; r[9]=c.y; r[10]=c.z; r[11]=c.w;
}

// ---------------- K1: feats + expfeat + featmax + gold ----------------
__global__ __launch_bounds__(256) void k_feats(
    const int* __restrict__ sentence, const int* __restrict__ tags,
    const float* __restrict__ emb, const float* __restrict__ W,
    const float* __restrict__ trans, float* __restrict__ ws)
{
  __shared__ float Wl[NTAGS * EMBD];
  __shared__ float gacc;
  for (int i = threadIdx.x; i < NTAGS * EMBD; i += 256) Wl[i] = W[i];
  if (threadIdx.x == 0) gacc = 0.f;
  __syncthreads();

  int grp = threadIdx.x >> 4;
  int g   = threadIdx.x & 15;
  int pos = blockIdx.x * 16 + grp;
  int row = sentence[pos];

  float acc = 0.f;
  if (g < R) {
    const float4* e4 = (const float4*)(emb + (size_t)row * EMBD);
    const float4* w4 = (const float4*)(Wl + g * EMBD);
    #pragma unroll 5
    for (int i = 0; i < EMBD / 4; ++i) {
      float4 a = e4[i]; float4 b = w4[i];
      acc += a.x*b.x + a.y*b.y + a.z*b.z + a.w*b.w;
    }
  }
  float feat = (g < R) ? acc : -3.0e38f;
  float mx = feat;
  #pragma unroll
  for (int off = 1; off < 16; off <<= 1)
    mx = fmaxf(mx, __shfl_xor(mx, off, 16));

  if (g < R) {
    ws[OFF_FEATS + pos * 12 + g] = feat;
    ws[OFF_EXPF  + pos * 12 + g] = __expf(feat - mx);
  }
  if (g == 0) ws[OFF_FMAX + pos] = mx;

  int tg = tags[pos];
  if (g == tg) {
    int prev = (pos == 0) ? T_START : tags[pos - 1];
    float gc = feat + trans[tg * NTAGS + prev];
    if (pos == LSEQ - 1) gc += trans[T_STOP * NTAGS + tg];
    atomicAdd(&gacc, gc);
  }
  __syncthreads();
  if (threadIdx.x == 0) atomicAdd(&ws[OFF_GOLD], gacc);
}

// ---------------- K2: chunk transfer matrices (prefetched) ----------------
__global__ __launch_bounds__(64, 1) void k_pass1(
    const float* __restrict__ trans, float* __restrict__ ws)
{
  int role = blockIdx.x >> 7;            // 0: LSE forward, 1: viterbi
  int q = threadIdx.x >> 4;
  int p = threadIdx.x & 15;
  int c = (blockIdx.x & 127) * 4 + q;
  int t0 = (c == 0) ? 1 : c * SCH;
  int t1 = c * SCH + SCH;
  bool act = (p < R);

  float Treg[R][R];

  if (role == 0) {
    #pragma unroll
    for (int n = 0; n < R; ++n)
      #pragma unroll
      for (int m = 0; m < R; ++m)
        Treg[n][m] = __expf(trans[n * NTAGS + m]);

    float E[R];
    #pragma unroll
    for (int m = 0; m < R; ++m) E[m] = (m == p) ? 1.f : 0.f;
    int kacc = 0;
    float sfeat = 0.f;

    float ef[R];
    load12(ws + OFF_EXPF + t0 * 12, ef);
    float fm = ws[OFF_FMAX + t0];

    for (int t = t0; t < t1; ++t) {
      float efn[R];
      load12(ws + OFF_EXPF + (t + 1) * 12, efn);   // off-end prefetch lands in FMAX region: safe
      float fmn = ws[OFF_FMAX + t + 1];
      sfeat += fm;
      float NE[R];
      #pragma unroll
      for (int n = 0; n < R; ++n) {
        float s = Treg[n][0] * E[0];
        #pragma unroll
        for (int m = 1; m < R; ++m) s = fmaf(Treg[n][m], E[m], s);
        NE[n] = s * ef[n];
      }
      #pragma unroll
      for (int n = 0; n < R; ++n) E[n] = NE[n];
      if ((t & 7) == 7) {
        float mx = E[0];
        #pragma unroll
        for (int n = 1; n < R; ++n) mx = fmaxf(mx, E[n]);
        if (mx > 0.f) {
          int k = ((__float_as_int(mx) >> 23) & 0xFF) - 127;
          float sc = __int_as_float((127 - k) << 23);
          #pragma unroll
          for (int n = 0; n < R; ++n) E[n] *= sc;
          kacc += k;
        }
      }
      #pragma unroll
      for (int n = 0; n < R; ++n) ef[n] = efn[n];
      fm = fmn;
    }
    if (act) {
      float base = (float)kacc * 0.6931471805599453f + sfeat;
      #pragma unroll
      for (int n = 0; n < R; ++n) {
        float v = (E[n] > 0.f) ? (__logf(E[n]) + base) : -1.0e30f;
        ws[OFF_PF  + c * 144 + n * 12 + p] = v;
        ws[OFF_PFC + c * 144 + p * 12 + n] = v;
      }
    }
  } else {
    #pragma unroll
    for (int n = 0; n < R; ++n)
      #pragma unroll
      for (int m = 0; m < R; ++m)
        Treg[n][m] = trans[n * NTAGS + m];

    float V[R];
    #pragma unroll
    for (int m = 0; m < R; ++m) V[m] = (m == p) ? 0.f : -1.0e30f;

    float fr[R];
    load12(ws + OFF_FEATS + t0 * 12, fr);

    for (int t = t0; t < t1; ++t) {
      float frn[R];
      load12(ws + OFF_FEATS + (t + 1) * 12, frn);  // off-end prefetch lands in EXPF region: safe
      float NV[R];
      #pragma unroll
      for (int n = 0; n < R; ++n) {
        float b = Treg[n][0] + V[0];
        #pragma unroll
        for (int m = 1; m < R; ++m) b = fmaxf(b, Treg[n][m] + V[m]);
        NV[n] = b + fr[n];
      }
      #pragma unroll
      for (int n = 0; n < R; ++n) { V[n] = NV[n]; fr[n] = frn[n]; }
    }
    if (act) {
      #pragma unroll
      for (int n = 0; n < R; ++n) {
        ws[OFF_PV  + c * 144 + n * 12 + p] = V[n];
        ws[OFF_PVC + c * 144 + p * 12 + n] = V[n];
      }
    }
  }
}

// ---------------- K2.5: super-chunk matrices, element-parallel ----------------
// One block per (super, sem): 64 blocks x 192 thr, lane l = (n,p) output elem.
// M and V staged through double-buffered LDS; 1 barrier per fold step.
__global__ __launch_bounds__(192) void k_super(
    float* __restrict__ ws)
{
  __shared__ float Ml[2][144];
  __shared__ float Vl[2][144];
  int s   = blockIdx.x >> 1;
  int sem = blockIdx.x & 1;              // 0: viterbi, 1: LSE
  int l = threadIdx.x;
  bool act = (l < 144);
  int n = l / 12;
  int p = l - n * 12;
  int base = sem ? OFF_PF : OFF_PV;

  float V = (act && n == p) ? 0.f : -1.0e30f;
  int buf = 0;
  for (int j = 0; j < CPS; ++j) {
    int c = s * CPS + j;
    if (act) {
      Ml[buf][l] = ws[base + c * 144 + l];
      Vl[buf][l] = V;
    }
    __syncthreads();
    if (act) {
      if (sem == 0) {
        float best = -3.0e38f;
        #pragma unroll
        for (int m = 0; m < R; ++m)
          best = fmaxf(best, Ml[buf][n * 12 + m] + Vl[buf][m * 12 + p]);
        V = best;
      } else {
        float cand[R]; float mx = -3.0e38f;
        #pragma unroll
        for (int m = 0; m < R; ++m) {
          cand[m] = Ml[buf][n * 12 + m] + Vl[buf][m * 12 + p];
          mx = fmaxf(mx, cand[m]);
        }
        float sum = 0.f;
        #pragma unroll
        for (int m = 0; m < R; ++m) sum += __expf(cand[m] - mx);
        V = mx + __logf(sum);
      }
    }
    buf ^= 1;
  }
  if (act) {
    if (sem == 0) {
      ws[OFF_SMV  + s * 144 + n * 12 + p] = V;
      ws[OFF_SMVT + s * 144 + p * 12 + n] = V;
    } else {
      ws[OFF_SMF + s * 144 + n * 12 + p] = V;
    }
  }
}

// ---------------- K3: sequential super-level scans (1 block, 3 waves) -------
// LDS broadcast (same-wave ds ordering, no barrier) + row prefetch.
__global__ __launch_bounds__(192) void k_mid(
    const float* __restrict__ trans, float* __restrict__ ws,
    float* __restrict__ out)
{
  __shared__ float Vsh[3][16];
  int wid  = threadIdx.x >> 6;
  int lane = threadIdx.x & 63;
  int n = lane;
  bool act = (n < R);

  if (wid == 0) {
    // Viterbi forward -> SBV + path_score
    float x = -3.0e38f;
    if (act) {
      x = trans[n * NTAGS + T_START] + ws[OFF_FEATS + n];
      ws[OFF_SBV + n] = x;
      Vsh[0][n] = x;
    }
    float row[R], rown[R];
    if (act) load12(ws + OFF_SMV + n * 12, row);
    for (int s = 0; s < NSUP; ++s) {
      if (act) load12(ws + OFF_SMV + (s + 1) * 144 + n * 12, rown); // s=31: lands in SMVT, unused
      float v[R];
      lds12(Vsh[0], v);
      if (act) {
        float nx = row[0] + v[0];
        #pragma unroll
        for (int m = 1; m < R; ++m) nx = fmaxf(nx, row[m] + v[m]);
        if (s < NSUP - 1) ws[OFF_SBV + (s + 1) * 12 + n] = nx;
        Vsh[0][n] = nx;
        #pragma unroll
        for (int m = 0; m < R; ++m) row[m] = rown[m];
      }
    }
    if (lane == 0) {
      float v[R];
      lds12(Vsh[0], v);
      float ps = -3.0e38f;
      #pragma unroll
      for (int m = 0; m < R; ++m) ps = fmaxf(ps, v[m] + trans[T_STOP * NTAGS + m]);
      out[1] = ps;
    }
  } else if (wid == 1) {
    // Viterbi suffix -> SSFX
    float x = -3.0e38f;
    if (act) {
      x = trans[T_STOP * NTAGS + n];
      ws[OFF_SSFX + (NSUP - 1) * 12 + n] = x;
      Vsh[1][n] = x;
    }
    float row[R], rown[R];
    if (act) load12(ws + OFF_SMVT + (NSUP - 1) * 144 + n * 12, row);
    for (int s = NSUP - 1; s >= 1; --s) {
      if (act) load12(ws + OFF_SMVT + (s - 1) * 144 + n * 12, rown); // s=1: row 0, valid
      float v[R];
      lds12(Vsh[1], v);
      if (act) {
        float nx = row[0] + v[0];
        #pragma unroll
        for (int m = 1; m < R; ++m) nx = fmaxf(nx, row[m] + v[m]);
        ws[OFF_SSFX + (s - 1) * 12 + n] = nx;
        Vsh[1][n] = nx;
        #pragma unroll
        for (int m = 0; m < R; ++m) row[m] = rown[m];
      }
    }
  } else if (wid == 2) {
    // LSE forward -> nll
    float x = -3.0e38f;
    if (act) {
      x = trans[n * NTAGS + T_START] + ws[OFF_FEATS + n];
      Vsh[2][n] = x;
    }
    float row[R], rown[R];
    if (act) load12(ws + OFF_SMF + n * 12, row);
    for (int s = 0; s < NSUP; ++s) {
      if (act) load12(ws + OFF_SMF + (s + 1) * 144 + n * 12, rown); // s=31: lands in SBV, unused
      float v[R];
      lds12(Vsh[2], v);
      if (act) {
        float tv[R]; float mx = -3.0e38f;
        #pragma unroll
        for (int m = 0; m < R; ++m) { tv[m] = row[m] + v[m]; mx = fmaxf(mx, tv[m]); }
        float sum = 0.f;
        #pragma unroll
        for (int m = 0; m < R; ++m) sum += __expf(tv[m] - mx);
        Vsh[2][n] = mx + __logf(sum);
        #pragma unroll
        for (int m = 0; m < R; ++m) row[m] = rown[m];
      }
    }
    if (lane == 0) {
      float v[R];
      lds12(Vsh[2], v);
      float mx = -3.0e38f;
      #pragma unroll
      for (int m = 0; m < R; ++m) mx = fmaxf(mx, v[m] + trans[T_STOP * NTAGS + m]);
      float sum = 0.f;
      #pragma unroll
      for (int m = 0; m < R; ++m) sum += __expf(v[m] + trans[T_STOP * NTAGS + m] - mx);
      out[0] = (mx + __logf(sum)) - ws[OFF_GOLD];
    }
  }
}

// ---------------- K3.5: expand super vectors to per-chunk BV / SFX ----------
// blocks 0..7: forward (entry) tasks; blocks 8..15: backward (suffix).
__global__ __launch_bounds__(64) void k_expand(
    float* __restrict__ ws)
{
  __shared__ float Vsh[4][16];
  int q = threadIdx.x >> 4;
  int g = threadIdx.x & 15;
  int dir = blockIdx.x >> 3;
  int s = (blockIdx.x & 7) * 4 + q;
  bool act = (g < R);

  if (dir == 0) {
    float x = -3.0e38f;
    if (act) {
      x = ws[OFF_SBV + s * 12 + g];
      ws[OFF_BV + (s * CPS) * 12 + g] = x;
      Vsh[q][g] = x;
    }
    float row[R], rown[R];
    if (act) load12(ws + OFF_PV + (s * CPS) * 144 + g * 12, row);
    for (int j = 0; j < CPS - 1; ++j) {
      int c = s * CPS + j;
      if (act) load12(ws + OFF_PV + (c + 1) * 144 + g * 12, rown);
      float v[R];
      lds12(Vsh[q], v);
      if (act) {
        float nx = row[0] + v[0];
        #pragma unroll
        for (int m = 1; m < R; ++m) nx = fmaxf(nx, row[m] + v[m]);
        ws[OFF_BV + (c + 1) * 12 + g] = nx;
        Vsh[q][g] = nx;
        #pragma unroll
        for (int m = 0; m < R; ++m) row[m] = rown[m];
      }
    }
  } else {
    float x = -3.0e38f;
    if (act) {
      x = ws[OFF_SSFX + s * 12 + g];
      ws[OFF_SFX + (s * CPS + CPS - 1) * 12 + g] = x;
      Vsh[q][g] = x;
    }
    float row[R], rown[R];
    if (act) load12(ws + OFF_PVC + (s * CPS + CPS - 1) * 144 + g * 12, row);
    for (int j = CPS - 1; j >= 1; --j) {
      int c = s * CPS + j;
      if (act) load12(ws + OFF_PVC + (c - 1) * 144 + g * 12, rown);
      float v[R];
      lds12(Vsh[q], v);
      if (act) {
        float nx = row[0] + v[0];
        #pragma unroll
        for (int m = 1; m < R; ++m) nx = fmaxf(nx, row[m] + v[m]);
        ws[OFF_SFX + (c - 1) * 12 + g] = nx;
        Vsh[q][g] = nx;
        #pragma unroll
        for (int m = 0; m < R; ++m) row[m] = rown[m];
      }
    }
  }
}

// ---------------- K4: per-chunk Viterbi decode (LDS broadcast + prefetch) ---
__global__ __launch_bounds__(64) void k_decode(
    const float* __restrict__ trans, const float* __restrict__ ws,
    float* __restrict__ out)
{
  __shared__ unsigned char bp[4][SCH][16];
  __shared__ float Vsh[4][16];
  int q = threadIdx.x >> 4;
  int g = threadIdx.x & 15;
  int c = blockIdx.x * 4 + q;
  int t0 = (c == 0) ? 1 : c * SCH;
  int t1 = c * SCH + SCH;
  bool act = (g < R);

  float treg[R];
  #pragma unroll
  for (int m = 0; m < R; ++m) treg[m] = act ? trans[g * NTAGS + m] : 0.f;

  float fv = act ? ws[OFF_BV + c * 12 + g] : -3.0e38f;
  Vsh[q][g] = fv;
  float fc = ws[OFF_FEATS + t0 * 12 + g];

  for (int t = t0; t < t1; ++t) {
    float fn = ws[OFF_FEATS + (t + 1) * 12 + g];   // off-end: EXPF region, unused
    float v[R];
    lds12(Vsh[q], v);
    float best = -3.0e38f; int bi = 0;
    #pragma unroll
    for (int m = 0; m < R; ++m) {
      float cand = treg[m] + v[m];
      if (cand > best) { best = cand; bi = m; }
    }
    float nfv = best + fc;
    if (act) {
      bp[q][t - t0][g] = (unsigned char)bi;
      Vsh[q][g] = nfv;
    }
    fc = fn;
  }

  Vsh[q][g] = act ? (Vsh[q][g] + ws[OFF_SFX + c * 12 + g]) : -3.0e38f;

  if (g == 0) {
    float best = Vsh[q][0]; int idx = 0;
    #pragma unroll
    for (int m = 1; m < R; ++m) {
      float v = Vsh[q][m];
      if (v > best) { best = v; idx = m; }
    }
    int cur = idx;
    int len = t1 - t0;
    out[2 + t0 + len - 1] = (float)cur;
    for (int tt = len - 1; tt >= 1; --tt) {
      cur = bp[q][tt][cur];
      out[2 + t0 + tt - 1] = (float)cur;
    }
    if (c == 0) {
      cur = bp[q][0][cur];
      out[2 + 0] = (float)cur;
    }
  }
}

extern "C" void kernel_launch(void* const* d_in, const int* in_sizes, int n_in,
                              void* d_out, int out_size, void* d_ws, size_t ws_size,
                              hipStream_t stream) {
  (void)in_sizes; (void)n_in; (void)out_size; (void)ws_size;
  const int*   sentence = (const int*)d_in[0];
  const int*   tags     = (const int*)d_in[1];
  const float* emb      = (const float*)d_in[2];
  const float* W        = (const float*)d_in[3];
  const float* trans    = (const float*)d_in[4];
  float* ws  = (float*)d_ws;
  float* out = (float*)d_out;

  hipMemsetAsync(ws + OFF_GOLD, 0, sizeof(float), stream);
  k_feats<<<LSEQ / 16, 256, 0, stream>>>(sentence, tags, emb, W, trans, ws);
  k_pass1<<<256, 64, 0, stream>>>(trans, ws);
  k_super<<<NSUP * 2, 192, 0, stream>>>(ws);
  k_mid<<<1, 192, 0, stream>>>(trans, ws, out);
  k_expand<<<16, 64, 0, stream>>>(ws);
  k_decode<<<CCH / 4, 64, 0, stream>>>(trans, ws, out);
}

// Round 4
// 277.577 us; speedup vs baseline: 1.7157x; 1.1030x over previous
//
#include <hip/hip_runtime.h>

// EmbeddingCRF: feats = emb[sentence] @ W^T; CRF forward (LSE), gold score,
// Viterbi decode. Parallel-in-time via 12x12 semiring transfer matrices.
// R4: 4-level scan tree — 2048 chunks(16 steps) -> 128 supers -> 8 hypers ->
// sequential 8 — so k_pass1 runs 4 waves/CU (was 1) and every serial chain
// is <= 16 steps. Register-prefetched folds, LDS broadcasts, no shuffles.

#define LSEQ    32768
#define NTAGS   14
#define R       12
#define T_START 12
#define T_STOP  13
#define EMBD    300
#define CCH     2048  // chunks
#define SCH     16    // steps per chunk
#define NSUP    128   // supers (16 chunks each)
#define NHYP    8     // hypers (16 supers each)

// ws layout (float offsets)
#define OFF_FEATS 0         // [L][12]
#define OFF_EXPF  393216    // [L][12]
#define OFF_FMAX  786432    // [L]
#define OFF_PF    819200    // [2048][n][p] LSE chunk mats (log domain)
#define OFF_PV    1114112   // [2048][n][p] max-plus chunk mats
#define OFF_PVC   1409024   // [2048][p][n] transposed
#define OFF_BV    1703936   // [2048][12] viterbi entry vectors
#define OFF_SFX   1728512   // [2048][12] viterbi suffix vectors
#define OFF_GOLD  1753088   // [1]
#define OFF_SMV   1753104   // [128][n][p]
#define OFF_SMVT  1771536   // [128][p][n]
#define OFF_SMF   1789968   // [128][n][p]
#define OFF_HMV   1808400   // [8][n][p]
#define OFF_HMVT  1809552   // [8][p][n]
#define OFF_HMF   1810704   // [8][n][p]
#define OFF_SBV   1811856   // [128][12]
#define OFF_SSFX  1813392   // [128][12]
#define OFF_HBV   1814928   // [8][12]
#define OFF_HSFX  1815024   // [8][12]

__device__ __forceinline__ void load12(const float* __restrict__ p, float* r) {
  const float4* p4 = (const float4*)p;
  float4 a = p4[0], b = p4[1], c = p4[2];
  r[0]=a.x; r[1]=a.y; r[2]=a.z; r[3]=a.w;
  r[4]=b.x; r[5]=b.y; r[6]=b.z; r[7]=b.w;
  r[8]=c.x; r[9]=c.y; r[10]=c.z; r[11]=c.w;
}

__device__ __forceinline__ void lds12(const float* p, float* r) {
  const float4* p4 = (const float4*)p;
  float4 a = p4[0], b = p4[1], c = p4[2];
  r[0]=a.x; r[1]=a.y; r[2]=a.z; r[3]=a.w;
  r[4]=b.x; r[5]=b.y; r[6]=b.z; r[7]=b.w;
  r[8]=c.x; r[9]=c.y; r[10]=c.z; r[11]=c.w;
}

// ---------------- K1: feats + expfeat + featmax + gold ----------------
__global__ __launch_bounds__(256) void k_feats(
    const int* __restrict__ sentence, const int* __restrict__ tags,
    const float* __restrict__ emb, const float* __restrict__ W,
    const float* __restrict__ trans, float* __restrict__ ws)
{
  __shared__ float Wl[NTAGS * EMBD];
  __shared__ float gacc;
  for (int i = threadIdx.x; i < NTAGS * EMBD; i += 256) Wl[i] = W[i];
  if (threadIdx.x == 0) gacc = 0.f;
  __syncthreads();

  int grp = threadIdx.x >> 4;
  int g   = threadIdx.x & 15;
  int pos = blockIdx.x * 16 + grp;
  int row = sentence[pos];

  float acc = 0.f;
  if (g < R) {
    const float4* e4 = (const float4*)(emb + (size_t)row * EMBD);
    const float4* w4 = (const float4*)(Wl + g * EMBD);
    #pragma unroll 5
    for (int i = 0; i < EMBD / 4; ++i) {
      float4 a = e4[i]; float4 b = w4[i];
      acc += a.x*b.x + a.y*b.y + a.z*b.z + a.w*b.w;
    }
  }
  float feat = (g < R) ? acc : -3.0e38f;
  float mx = feat;
  #pragma unroll
  for (int off = 1; off < 16; off <<= 1)
    mx = fmaxf(mx, __shfl_xor(mx, off, 16));

  if (g < R) {
    ws[OFF_FEATS + pos * 12 + g] = feat;
    ws[OFF_EXPF  + pos * 12 + g] = __expf(feat - mx);
  }
  if (g == 0) ws[OFF_FMAX + pos] = mx;

  int tg = tags[pos];
  if (g == tg) {
    int prev = (pos == 0) ? T_START : tags[pos - 1];
    float gc = feat + trans[tg * NTAGS + prev];
    if (pos == LSEQ - 1) gc += trans[T_STOP * NTAGS + tg];
    atomicAdd(&gacc, gc);
  }
  __syncthreads();
  if (threadIdx.x == 0) atomicAdd(&ws[OFF_GOLD], gacc);
}

// ---------------- K2: chunk transfer matrices (16 steps, prefetched) --------
// 1024 blocks x 64 thr: blocks 0..511 LSE, 512..1023 viterbi; 4 chunks/block.
__global__ __launch_bounds__(64) void k_pass1(
    const float* __restrict__ trans, float* __restrict__ ws)
{
  int role = blockIdx.x >> 9;
  int q = threadIdx.x >> 4;
  int p = threadIdx.x & 15;
  int c = (blockIdx.x & 511) * 4 + q;
  int t0 = (c == 0) ? 1 : c * SCH;
  int t1 = c * SCH + SCH;
  bool act = (p < R);

  float Treg[R][R];

  if (role == 0) {
    #pragma unroll
    for (int n = 0; n < R; ++n)
      #pragma unroll
      for (int m = 0; m < R; ++m)
        Treg[n][m] = __expf(trans[n * NTAGS + m]);

    float E[R];
    #pragma unroll
    for (int m = 0; m < R; ++m) E[m] = (m == p) ? 1.f : 0.f;
    int kacc = 0;
    float sfeat = 0.f;

    float ef[R];
    load12(ws + OFF_EXPF + t0 * 12, ef);
    float fm = ws[OFF_FMAX + t0];

    for (int t = t0; t < t1; ++t) {
      float efn[R];
      load12(ws + OFF_EXPF + (t + 1) * 12, efn);   // off-end lands in FMAX: safe
      float fmn = ws[OFF_FMAX + t + 1];            // off-end lands in PF: safe
      sfeat += fm;
      float NE[R];
      #pragma unroll
      for (int n = 0; n < R; ++n) {
        float s = Treg[n][0] * E[0];
        #pragma unroll
        for (int m = 1; m < R; ++m) s = fmaf(Treg[n][m], E[m], s);
        NE[n] = s * ef[n];
      }
      #pragma unroll
      for (int n = 0; n < R; ++n) E[n] = NE[n];
      if ((t & 7) == 7) {
        float mx = E[0];
        #pragma unroll
        for (int n = 1; n < R; ++n) mx = fmaxf(mx, E[n]);
        if (mx > 0.f) {
          int k = ((__float_as_int(mx) >> 23) & 0xFF) - 127;
          float sc = __int_as_float((127 - k) << 23);
          #pragma unroll
          for (int n = 0; n < R; ++n) E[n] *= sc;
          kacc += k;
        }
      }
      #pragma unroll
      for (int n = 0; n < R; ++n) ef[n] = efn[n];
      fm = fmn;
    }
    if (act) {
      float base = (float)kacc * 0.6931471805599453f + sfeat;
      #pragma unroll
      for (int n = 0; n < R; ++n) {
        float v = (E[n] > 0.f) ? (__logf(E[n]) + base) : -1.0e30f;
        ws[OFF_PF + c * 144 + n * 12 + p] = v;
      }
    }
  } else {
    #pragma unroll
    for (int n = 0; n < R; ++n)
      #pragma unroll
      for (int m = 0; m < R; ++m)
        Treg[n][m] = trans[n * NTAGS + m];

    float V[R];
    #pragma unroll
    for (int m = 0; m < R; ++m) V[m] = (m == p) ? 0.f : -1.0e30f;

    float fr[R];
    load12(ws + OFF_FEATS + t0 * 12, fr);

    for (int t = t0; t < t1; ++t) {
      float frn[R];
      load12(ws + OFF_FEATS + (t + 1) * 12, frn);  // off-end lands in EXPF: safe
      float NV[R];
      #pragma unroll
      for (int n = 0; n < R; ++n) {
        float b = Treg[n][0] + V[0];
        #pragma unroll
        for (int m = 1; m < R; ++m) b = fmaxf(b, Treg[n][m] + V[m]);
        NV[n] = b + fr[n];
      }
      #pragma unroll
      for (int n = 0; n < R; ++n) { V[n] = NV[n]; fr[n] = frn[n]; }
    }
    if (act) {
      #pragma unroll
      for (int n = 0; n < R; ++n) {
        ws[OFF_PV  + c * 144 + n * 12 + p] = V[n];
        ws[OFF_PVC + c * 144 + p * 12 + n] = V[n];
      }
    }
  }
}

// ---------------- K_fold: 16-way semiring matrix fold (generic level) -------
// grid = Nout*2; blockIdx&1: 0 = viterbi (srcV -> dstV+dstVT), 1 = LSE.
// 192 thr, thread l = output element (n,p); next matrix register-prefetched.
__global__ __launch_bounds__(192) void k_fold(
    float* __restrict__ ws, int srcV, int srcF, int dstV, int dstVT, int dstF)
{
  __shared__ float Ml[144];
  __shared__ float Vl[144];
  int s   = blockIdx.x >> 1;
  int sem = blockIdx.x & 1;
  int l = threadIdx.x;
  bool act = (l < 144);
  int n = l / 12;
  int p = l - n * 12;
  int base = sem ? srcF : srcV;

  float V = (act && n == p) ? 0.f : -1.0e30f;
  float mreg = act ? ws[base + (s * 16) * 144 + l] : 0.f;

  for (int j = 0; j < 16; ++j) {
    if (act) { Ml[l] = mreg; Vl[l] = V; }
    __syncthreads();
    if (act) mreg = ws[base + (s * 16 + j + 1) * 144 + l];  // off-end: next region, safe
    if (act) {
      if (sem == 0) {
        float best = -3.0e38f;
        #pragma unroll
        for (int m = 0; m < R; ++m)
          best = fmaxf(best, Ml[n * 12 + m] + Vl[m * 12 + p]);
        V = best;
      } else {
        float cand[R]; float mx = -3.0e38f;
        #pragma unroll
        for (int m = 0; m < R; ++m) {
          cand[m] = Ml[n * 12 + m] + Vl[m * 12 + p];
          mx = fmaxf(mx, cand[m]);
        }
        float sum = 0.f;
        #pragma unroll
        for (int m = 0; m < R; ++m) sum += __expf(cand[m] - mx);
        V = mx + __logf(sum);
      }
    }
    __syncthreads();
  }
  if (act) {
    if (sem == 0) {
      ws[dstV  + s * 144 + n * 12 + p] = V;
      ws[dstVT + s * 144 + p * 12 + n] = V;
    } else {
      ws[dstF + s * 144 + n * 12 + p] = V;
    }
  }
}

// ---------------- K_mid: sequential hyper-level scans (1 block, 3 waves) ----
__global__ __launch_bounds__(192) void k_mid(
    const float* __restrict__ trans, float* __restrict__ ws,
    float* __restrict__ out)
{
  __shared__ float Vsh[3][16];
  int wid  = threadIdx.x >> 6;
  int lane = threadIdx.x & 63;
  int n = lane;
  bool act = (n < R);

  if (wid == 0) {
    // Viterbi forward -> HBV + path_score
    float x = -3.0e38f;
    if (act) {
      x = trans[n * NTAGS + T_START] + ws[OFF_FEATS + n];
      ws[OFF_HBV + n] = x;
      Vsh[0][n] = x;
    }
    float row[R], rown[R];
    if (act) load12(ws + OFF_HMV + n * 12, row);
    for (int h = 0; h < NHYP; ++h) {
      if (act) load12(ws + OFF_HMV + (h + 1) * 144 + n * 12, rown); // h=7: HMVT, unused
      float v[R];
      lds12(Vsh[0], v);
      if (act) {
        float nx = row[0] + v[0];
        #pragma unroll
        for (int m = 1; m < R; ++m) nx = fmaxf(nx, row[m] + v[m]);
        if (h < NHYP - 1) ws[OFF_HBV + (h + 1) * 12 + n] = nx;
        Vsh[0][n] = nx;
        #pragma unroll
        for (int m = 0; m < R; ++m) row[m] = rown[m];
      }
    }
    if (lane == 0) {
      float v[R];
      lds12(Vsh[0], v);
      float ps = -3.0e38f;
      #pragma unroll
      for (int m = 0; m < R; ++m) ps = fmaxf(ps, v[m] + trans[T_STOP * NTAGS + m]);
      out[1] = ps;
    }
  } else if (wid == 1) {
    // Viterbi suffix -> HSFX
    float x = -3.0e38f;
    if (act) {
      x = trans[T_STOP * NTAGS + n];
      ws[OFF_HSFX + (NHYP - 1) * 12 + n] = x;
      Vsh[1][n] = x;
    }
    float row[R], rown[R];
    if (act) load12(ws + OFF_HMVT + (NHYP - 1) * 144 + n * 12, row);
    for (int h = NHYP - 1; h >= 1; --h) {
      if (act) load12(ws + OFF_HMVT + (h - 1) * 144 + n * 12, rown);
      float v[R];
      lds12(Vsh[1], v);
      if (act) {
        float nx = row[0] + v[0];
        #pragma unroll
        for (int m = 1; m < R; ++m) nx = fmaxf(nx, row[m] + v[m]);
        ws[OFF_HSFX + (h - 1) * 12 + n] = nx;
        Vsh[1][n] = nx;
        #pragma unroll
        for (int m = 0; m < R; ++m) row[m] = rown[m];
      }
    }
  } else if (wid == 2) {
    // LSE forward -> nll
    float x = -3.0e38f;
    if (act) {
      x = trans[n * NTAGS + T_START] + ws[OFF_FEATS + n];
      Vsh[2][n] = x;
    }
    float row[R], rown[R];
    if (act) load12(ws + OFF_HMF + n * 12, row);
    for (int h = 0; h < NHYP; ++h) {
      if (act) load12(ws + OFF_HMF + (h + 1) * 144 + n * 12, rown); // h=7: SBV, unused
      float v[R];
      lds12(Vsh[2], v);
      if (act) {
        float tv[R]; float mx = -3.0e38f;
        #pragma unroll
        for (int m = 0; m < R; ++m) { tv[m] = row[m] + v[m]; mx = fmaxf(mx, tv[m]); }
        float sum = 0.f;
        #pragma unroll
        for (int m = 0; m < R; ++m) sum += __expf(tv[m] - mx);
        Vsh[2][n] = mx + __logf(sum);
        #pragma unroll
        for (int m = 0; m < R; ++m) row[m] = rown[m];
      }
    }
    if (lane == 0) {
      float v[R];
      lds12(Vsh[2], v);
      float mx = -3.0e38f;
      #pragma unroll
      for (int m = 0; m < R; ++m) mx = fmaxf(mx, v[m] + trans[T_STOP * NTAGS + m]);
      float sum = 0.f;
      #pragma unroll
      for (int m = 0; m < R; ++m) sum += __expf(v[m] + trans[T_STOP * NTAGS + m] - mx);
      out[0] = (mx + __logf(sum)) - ws[OFF_GOLD];
    }
  }
}

// ---------------- K_expandA: hyper vectors -> super vectors ----------------
// 16 tasks (8 hyper x 2 dir), 4 per block.
__global__ __launch_bounds__(64) void k_expandA(
    float* __restrict__ ws)
{
  __shared__ float Vsh[4][16];
  int q = threadIdx.x >> 4;
  int g = threadIdx.x & 15;
  int task = blockIdx.x * 4 + q;
  int h = task >> 1;
  int dir = task & 1;
  bool act = (g < R);

  if (dir == 0) {
    float x = -3.0e38f;
    if (act) {
      x = ws[OFF_HBV + h * 12 + g];
      ws[OFF_SBV + (h * 16) * 12 + g] = x;
      Vsh[q][g] = x;
    }
    float row[R], rown[R];
    if (act) load12(ws + OFF_SMV + (h * 16) * 144 + g * 12, row);
    for (int j = 0; j < 15; ++j) {
      int s = h * 16 + j;
      if (act) load12(ws + OFF_SMV + (s + 1) * 144 + g * 12, rown);
      float v[R];
      lds12(Vsh[q], v);
      if (act) {
        float nx = row[0] + v[0];
        #pragma unroll
        for (int m = 1; m < R; ++m) nx = fmaxf(nx, row[m] + v[m]);
        ws[OFF_SBV + (s + 1) * 12 + g] = nx;
        Vsh[q][g] = nx;
        #pragma unroll
        for (int m = 0; m < R; ++m) row[m] = rown[m];
      }
    }
  } else {
    float x = -3.0e38f;
    if (act) {
      x = ws[OFF_HSFX + h * 12 + g];
      ws[OFF_SSFX + (h * 16 + 15) * 12 + g] = x;
      Vsh[q][g] = x;
    }
    float row[R], rown[R];
    if (act) load12(ws + OFF_SMVT + (h * 16 + 15) * 144 + g * 12, row);
    for (int j = 15; j >= 1; --j) {
      int s = h * 16 + j;
      if (act) load12(ws + OFF_SMVT + (s - 1) * 144 + g * 12, rown);
      float v[R];
      lds12(Vsh[q], v);
      if (act) {
        float nx = row[0] + v[0];
        #pragma unroll
        for (int m = 1; m < R; ++m) nx = fmaxf(nx, row[m] + v[m]);
        ws[OFF_SSFX + (s - 1) * 12 + g] = nx;
        Vsh[q][g] = nx;
        #pragma unroll
        for (int m = 0; m < R; ++m) row[m] = rown[m];
      }
    }
  }
}

// ---------------- K_expandB: super vectors -> chunk vectors ----------------
// 256 tasks (128 super x 2 dir), 4 per block.
__global__ __launch_bounds__(64) void k_expandB(
    float* __restrict__ ws)
{
  __shared__ float Vsh[4][16];
  int q = threadIdx.x >> 4;
  int g = threadIdx.x & 15;
  int task = blockIdx.x * 4 + q;
  int s = task >> 1;
  int dir = task & 1;
  bool act = (g < R);

  if (dir == 0) {
    float x = -3.0e38f;
    if (act) {
      x = ws[OFF_SBV + s * 12 + g];
      ws[OFF_BV + (s * 16) * 12 + g] = x;
      Vsh[q][g] = x;
    }
    float row[R], rown[R];
    if (act) load12(ws + OFF_PV + (s * 16) * 144 + g * 12, row);
    for (int j = 0; j < 15; ++j) {
      int c = s * 16 + j;
      if (act) load12(ws + OFF_PV + (c + 1) * 144 + g * 12, rown);
      float v[R];
      lds12(Vsh[q], v);
      if (act) {
        float nx = row[0] + v[0];
        #pragma unroll
        for (int m = 1; m < R; ++m) nx = fmaxf(nx, row[m] + v[m]);
        ws[OFF_BV + (c + 1) * 12 + g] = nx;
        Vsh[q][g] = nx;
        #pragma unroll
        for (int m = 0; m < R; ++m) row[m] = rown[m];
      }
    }
  } else {
    float x = -3.0e38f;
    if (act) {
      x = ws[OFF_SSFX + s * 12 + g];
      ws[OFF_SFX + (s * 16 + 15) * 12 + g] = x;
      Vsh[q][g] = x;
    }
    float row[R], rown[R];
    if (act) load12(ws + OFF_PVC + (s * 16 + 15) * 144 + g * 12, row);
    for (int j = 15; j >= 1; --j) {
      int c = s * 16 + j;
      if (act) load12(ws + OFF_PVC + (c - 1) * 144 + g * 12, rown);
      float v[R];
      lds12(Vsh[q], v);
      if (act) {
        float nx = row[0] + v[0];
        #pragma unroll
        for (int m = 1; m < R; ++m) nx = fmaxf(nx, row[m] + v[m]);
        ws[OFF_SFX + (c - 1) * 12 + g] = nx;
        Vsh[q][g] = nx;
        #pragma unroll
        for (int m = 0; m < R; ++m) row[m] = rown[m];
      }
    }
  }
}

// ---------------- K_decode: per-chunk Viterbi re-scan + local backtrace -----
__global__ __launch_bounds__(64) void k_decode(
    const float* __restrict__ trans, const float* __restrict__ ws,
    float* __restrict__ out)
{
  __shared__ unsigned char bp[4][SCH][16];
  __shared__ float Vsh[4][16];
  int q = threadIdx.x >> 4;
  int g = threadIdx.x & 15;
  int c = blockIdx.x * 4 + q;
  int t0 = (c == 0) ? 1 : c * SCH;
  int t1 = c * SCH + SCH;
  bool act = (g < R);

  float treg[R];
  #pragma unroll
  for (int m = 0; m < R; ++m) treg[m] = act ? trans[g * NTAGS + m] : 0.f;

  float fv = act ? ws[OFF_BV + c * 12 + g] : -3.0e38f;
  Vsh[q][g] = fv;
  float fc = ws[OFF_FEATS + t0 * 12 + g];

  for (int t = t0; t < t1; ++t) {
    float fn = ws[OFF_FEATS + (t + 1) * 12 + g];   // off-end: EXPF, unused
    float v[R];
    lds12(Vsh[q], v);
    float best = -3.0e38f; int bi = 0;
    #pragma unroll
    for (int m = 0; m < R; ++m) {
      float cand = treg[m] + v[m];
      if (cand > best) { best = cand; bi = m; }
    }
    float nfv = best + fc;
    if (act) {
      bp[q][t - t0][g] = (unsigned char)bi;
      Vsh[q][g] = nfv;
    }
    fc = fn;
  }

  Vsh[q][g] = act ? (Vsh[q][g] + ws[OFF_SFX + c * 12 + g]) : -3.0e38f;

  if (g == 0) {
    float best = Vsh[q][0]; int idx = 0;
    #pragma unroll
    for (int m = 1; m < R; ++m) {
      float v = Vsh[q][m];
      if (v > best) { best = v; idx = m; }
    }
    int cur = idx;
    int len = t1 - t0;
    out[2 + t0 + len - 1] = (float)cur;
    for (int tt = len - 1; tt >= 1; --tt) {
      cur = bp[q][tt][cur];
      out[2 + t0 + tt - 1] = (float)cur;
    }
    if (c == 0) {
      cur = bp[q][0][cur];
      out[2 + 0] = (float)cur;
    }
  }
}

extern "C" void kernel_launch(void* const* d_in, const int* in_sizes, int n_in,
                              void* d_out, int out_size, void* d_ws, size_t ws_size,
                              hipStream_t stream) {
  (void)in_sizes; (void)n_in; (void)out_size; (void)ws_size;
  const int*   sentence = (const int*)d_in[0];
  const int*   tags     = (const int*)d_in[1];
  const float* emb      = (const float*)d_in[2];
  const float* W        = (const float*)d_in[3];
  const float* trans    = (const float*)d_in[4];
  float* ws  = (float*)d_ws;
  float* out = (float*)d_out;

  hipMemsetAsync(ws + OFF_GOLD, 0, sizeof(float), stream);
  k_feats<<<LSEQ / 16, 256, 0, stream>>>(sentence, tags, emb, W, trans, ws);
  k_pass1<<<1024, 64, 0, stream>>>(trans, ws);
  k_fold<<<NSUP * 2, 192, 0, stream>>>(ws, OFF_PV, OFF_PF, OFF_SMV, OFF_SMVT, OFF_SMF);
  k_fold<<<NHYP * 2, 192, 0, stream>>>(ws, OFF_SMV, OFF_SMF, OFF_HMV, OFF_HMVT, OFF_HMF);
  k_mid<<<1, 192, 0, stream>>>(trans, ws, out);
  k_expandA<<<4, 64, 0, stream>>>(ws);
  k_expandB<<<64, 64, 0, stream>>>(ws);
  k_decode<<<CCH / 4, 64, 0, stream>>>(trans, ws, out);
}